// Round 7
// baseline (171.513 us; speedup 1.0000x reference)
//
#include <hip/hip_runtime.h>
#include <hip/hip_bf16.h>

#define NTOK 64
#define CDIM 128
#define SCALE 0.17677669529663688f   // 1/sqrt(32)

typedef __attribute__((ext_vector_type(4))) float  f32x4;
typedef __attribute__((ext_vector_type(8))) short  bf16x8;
typedef __attribute__((ext_vector_type(4))) short  s16x4;

__device__ __forceinline__ s16x4 pk4(f32x4 v) {
  union { __hip_bfloat162 h[2]; s16x4 s; } u;
  u.h[0] = __float22bfloat162_rn(float2{v.x, v.y});
  u.h[1] = __float22bfloat162_rn(float2{v.z, v.w});
  return u.s;
}

// XOR-swizzle within a row: 16B granule, 3 row bits
__device__ __forceinline__ int swz(int row, int cb, int stride) {
  return row * stride + (cb ^ ((row & 7) << 4));
}

__global__ void wconv_kernel(const float* __restrict__ wq, const float* __restrict__ wk,
                             const float* __restrict__ wv, const float* __restrict__ wo,
                             short* __restrict__ wbf) {
  int t = (blockIdx.x * 256 + threadIdx.x) * 4;   // 16 blocks
  f32x4 a = *reinterpret_cast<const f32x4*>(wq + t);
  f32x4 b = *reinterpret_cast<const f32x4*>(wk + t);
  f32x4 c = *reinterpret_cast<const f32x4*>(wv + t);
  f32x4 d = *reinterpret_cast<const f32x4*>(wo + t);
  *reinterpret_cast<s16x4*>(wbf + t)         = pk4(a);
  *reinterpret_cast<s16x4*>(wbf + 16384 + t) = pk4(b);
  *reinterpret_cast<s16x4*>(wbf + 32768 + t) = pk4(c);
  *reinterpret_cast<s16x4*>(wbf + 49152 + t) = pk4(d);
}

// LDS 48K, R2's proven region plan, per pipelined batch:
//   A [0,16K):   X -> Q -> P(h0,h1) -> X(next batch)
//   B [16K,32K): K -> P(h2,h3)
//   C [32K,48K): Vt -> O
#define A_OFF 0
#define B_OFF 16384
#define C_OFF 32768
#define SMEM_BYTES 49152

__global__ __launch_bounds__(256, 3) void fused_attn(
    const float* __restrict__ x, const float* __restrict__ ent,
    const short* __restrict__ wbf,
    const float* __restrict__ bq, const float* __restrict__ bk,
    const float* __restrict__ bv, const float* __restrict__ bo,
    const int* __restrict__ beta, float* __restrict__ out)
{
  __shared__ unsigned char sm[SMEM_BYTES];
  const int tid  = threadIdx.x;
  const int lane = tid & 63;
  const int w    = tid >> 6;        // wave id 0..3 (= head id in attn phases)
  const int g    = lane >> 4;       // 16-lane group 0..3
  const int li   = lane & 15;

  const int b0 = blockIdx.x;
  const int b1 = blockIdx.x + gridDim.x;   // second pipelined batch

  f32x4 xn[8];   // in-flight x(b1) (issued early, consumed late)

  // ---------- stage X(b0) (fp32 -> bf16, swizzled) into A ----------
  {
    const float* xb = x + (size_t)b0 * (NTOK * CDIM);
    #pragma unroll
    for (int i = 0; i < 8; ++i) {
      int f = (tid + 256 * i) * 4;
      int row = f >> 7, col = f & 127;
      f32x4 v = *reinterpret_cast<const f32x4*>(xb + f);
      *reinterpret_cast<s16x4*>(sm + A_OFF + swz(row, col * 2, 256)) = pk4(v);
    }
  }
  __syncthreads();   // X(b0) staged in A

  const f32x4 zero4 = {0.f, 0.f, 0.f, 0.f};

  #define LDA(t, kk) (*reinterpret_cast<const bf16x8*>( \
      sm + A_OFF + swz((t) * 16 + li, ((kk) * 32 + g * 8) * 2, 256)))

  auto run = [&](int bb, bool prefetch_next, int bnext) {
    // ---- 1. preload X fragments from A; issue next batch's x loads ----
    bf16x8 xf[4][4];
    #pragma unroll
    for (int ti = 0; ti < 4; ++ti)
      #pragma unroll
      for (int kk = 0; kk < 4; ++kk)
        xf[ti][kk] = LDA(ti, kk);
    if (prefetch_next) {
      const float* xb = x + (size_t)bnext * (NTOK * CDIM);
      #pragma unroll
      for (int i = 0; i < 8; ++i)
        xn[i] = *reinterpret_cast<const f32x4*>(xb + (tid + 256 * i) * 4);
    }
    __syncthreads();   // Bp: X in regs; A may be overwritten

    // ---- 2a. V (wave w -> d in [32w,32w+32)) -> Vt in C ----
    {
      const short* wv_ = wbf + 32768;
      f32x4 accv[4][2];
      #pragma unroll
      for (int mi = 0; mi < 4; ++mi) { accv[mi][0] = zero4; accv[mi][1] = zero4; }
      bf16x8 bfv[2][4];
      #pragma unroll
      for (int n2 = 0; n2 < 2; ++n2)
        #pragma unroll
        for (int kk = 0; kk < 4; ++kk)
          bfv[n2][kk] = *reinterpret_cast<const bf16x8*>(wv_ + (w * 32 + n2 * 16 + li) * CDIM + kk * 32 + g * 8);
      #pragma unroll
      for (int mi = 0; mi < 4; ++mi)
        #pragma unroll
        for (int n2 = 0; n2 < 2; ++n2)
          #pragma unroll
          for (int kk = 0; kk < 4; ++kk)
            accv[mi][n2] = __builtin_amdgcn_mfma_f32_16x16x32_bf16(xf[mi][kk], bfv[n2][kk], accv[mi][n2], 0, 0, 0);
      #pragma unroll
      for (int mi = 0; mi < 4; ++mi)
        #pragma unroll
        for (int n2 = 0; n2 < 2; ++n2) {
          int d = w * 32 + n2 * 16 + li;
          float bb_ = bv[d];
          f32x4 v = accv[mi][n2];
          v.x += bb_; v.y += bb_; v.z += bb_; v.w += bb_;
          *reinterpret_cast<s16x4*>(sm + C_OFF + swz(d, (mi * 16 + g * 4) * 2, 128)) = pk4(v);
        }
    }

    // ---- 2b. Q,K (swapped: Dt = W * X^T): waves 0,1 -> Q->A ; 2,3 -> K->B ----
    {
      const short* wmat = wbf + ((w < 2) ? 0 : 16384);
      const float* bias = (w < 2) ? bq : bk;
      const float bsc   = (w < 2) ? SCALE : 1.0f;
      const int dbase   = (w & 1) * 64;
      const int qkoff   = (w < 2) ? A_OFF : B_OFF;
      #pragma unroll
      for (int mi = 0; mi < 4; ++mi) {
        bf16x8 af[4];
        #pragma unroll
        for (int kk = 0; kk < 4; ++kk)
          af[kk] = *reinterpret_cast<const bf16x8*>(wmat + (dbase + mi * 16 + li) * CDIM + kk * 32 + g * 8);
        f32x4 acc[4];
        #pragma unroll
        for (int ni = 0; ni < 4; ++ni) acc[ni] = zero4;
        #pragma unroll
        for (int ni = 0; ni < 4; ++ni)
          #pragma unroll
          for (int kk = 0; kk < 4; ++kk)
            acc[ni] = __builtin_amdgcn_mfma_f32_16x16x32_bf16(af[kk], xf[ni][kk], acc[ni], 0, 0, 0);
        int d0 = dbase + mi * 16 + g * 4;
        float4 b4 = *reinterpret_cast<const float4*>(bias + d0);
        b4.x *= bsc; b4.y *= bsc; b4.z *= bsc; b4.w *= bsc;
        #pragma unroll
        for (int ni = 0; ni < 4; ++ni) {
          f32x4 v = acc[ni];
          v.x = v.x * bsc + b4.x; v.y = v.y * bsc + b4.y;
          v.z = v.z * bsc + b4.z; v.w = v.w * bsc + b4.w;
          *reinterpret_cast<s16x4*>(sm + qkoff + swz(ni * 16 + li, d0 * 2, 256)) = pk4(v);
        }
      }
    }
    __syncthreads();   // Bq: Q,K,Vt ready

    // ---- 3. scores (St = K * Q^T) + no-max softmax (validated R4/R6) ----
    f32x4 st[4][4];
    {
      bf16x8 kf[4], qf[4];
      int cb = (w * 32 + g * 8) * 2;
      #pragma unroll
      for (int t = 0; t < 4; ++t) {
        kf[t] = *reinterpret_cast<const bf16x8*>(sm + B_OFF + swz(t * 16 + li, cb, 256));
        qf[t] = *reinterpret_cast<const bf16x8*>(sm + A_OFF + swz(t * 16 + li, cb, 256));
      }
      #pragma unroll
      for (int mj = 0; mj < 4; ++mj)
        #pragma unroll
        for (int ni = 0; ni < 4; ++ni)
          st[mj][ni] = __builtin_amdgcn_mfma_f32_16x16x32_bf16(kf[mj], qf[ni], zero4, 0, 0, 0);
    }
    float4 gv[4];
    {
      const float nb = -(float)beta[0];
      const float* eb = ent + (size_t)bb * NTOK;
      #pragma unroll
      for (int mj = 0; mj < 4; ++mj) {
        float4 e = *reinterpret_cast<const float4*>(eb + mj * 16 + g * 4);
        gv[mj].x = nb * e.x; gv[mj].y = nb * e.y; gv[mj].z = nb * e.z; gv[mj].w = nb * e.w;
      }
    }
    #pragma unroll
    for (int ni = 0; ni < 4; ++ni) {
      float sum = 0.f;
      #pragma unroll
      for (int mj = 0; mj < 4; ++mj) {
        f32x4 v = st[mj][ni];
        v.x = __expf(v.x + gv[mj].x); v.y = __expf(v.y + gv[mj].y);
        v.z = __expf(v.z + gv[mj].z); v.w = __expf(v.w + gv[mj].w);
        st[mj][ni] = v;
        sum += v.x + v.y + v.z + v.w;
      }
      sum += __shfl_xor(sum, 16);
      sum += __shfl_xor(sum, 32);
      float inv = 1.f / (sum + 1e-9f);
      #pragma unroll
      for (int mj = 0; mj < 4; ++mj) {
        st[mj][ni].x *= inv; st[mj][ni].y *= inv;
        st[mj][ni].z *= inv; st[mj][ni].w *= inv;
      }
    }
    __syncthreads();   // Br: Q/K reads done; A,B reusable for P

    // P^T regs -> P[i][j] (head w at sm + w*8192, spans A then B)
    unsigned char* pb = sm + w * 8192;
    #pragma unroll
    for (int mj = 0; mj < 4; ++mj) {
      int cb = (mj * 16 + g * 4) * 2;
      #pragma unroll
      for (int ni = 0; ni < 4; ++ni)
        *reinterpret_cast<s16x4*>(pb + swz(ni * 16 + li, cb, 128)) = pk4(st[mj][ni]);
    }

    // ---- 4. PV (Ot = Vt * P^T) ----
    f32x4 accO[2][4];
    #pragma unroll
    for (int md = 0; md < 2; ++md)
      #pragma unroll
      for (int ni = 0; ni < 4; ++ni) accO[md][ni] = zero4;
    {
      bf16x8 vf[2][2];
      #pragma unroll
      for (int md = 0; md < 2; ++md)
        #pragma unroll
        for (int ks = 0; ks < 2; ++ks)
          vf[md][ks] = *reinterpret_cast<const bf16x8*>(sm + C_OFF + swz(w * 32 + md * 16 + li, (ks * 32 + g * 8) * 2, 128));
      bf16x8 pf[4][2];
      #pragma unroll
      for (int ni = 0; ni < 4; ++ni)
        #pragma unroll
        for (int ks = 0; ks < 2; ++ks)
          pf[ni][ks] = *reinterpret_cast<const bf16x8*>(pb + swz(ni * 16 + li, (ks * 32 + g * 8) * 2, 128));
      #pragma unroll
      for (int md = 0; md < 2; ++md)
        #pragma unroll
        for (int ni = 0; ni < 4; ++ni)
          #pragma unroll
          for (int ks = 0; ks < 2; ++ks)
            accO[md][ni] = __builtin_amdgcn_mfma_f32_16x16x32_bf16(vf[md][ks], pf[ni][ks], accO[md][ni], 0, 0, 0);
    }
    __syncthreads();   // Bs: PV reads done; A free for next-X, C free for O

    // ---- 5. O -> C; deferred write of next batch's X -> A ----
    #pragma unroll
    for (int md = 0; md < 2; ++md) {
      int cb = (w * 32 + md * 16 + g * 4) * 2;
      #pragma unroll
      for (int ni = 0; ni < 4; ++ni)
        *reinterpret_cast<s16x4*>(sm + C_OFF + swz(ni * 16 + li, cb, 256)) = pk4(accO[md][ni]);
    }
    if (prefetch_next) {
      #pragma unroll
      for (int i = 0; i < 8; ++i) {
        int f = (tid + 256 * i) * 4;
        int row = f >> 7, col = f & 127;
        *reinterpret_cast<s16x4*>(sm + A_OFF + swz(row, col * 2, 256)) = pk4(xn[i]);
      }
    }
    __syncthreads();   // Bt: O ready (and next-X staged)

    // ---- 6. out-proj swapped (Yt = Wo * O^T) -> float4 stores ----
    {
      const short* wo_ = wbf + 49152;
      f32x4 accY[2][4];
      #pragma unroll
      for (int mi = 0; mi < 2; ++mi)
        #pragma unroll
        for (int ni = 0; ni < 4; ++ni) accY[mi][ni] = zero4;
      bf16x8 wfa[2][4];
      #pragma unroll
      for (int mi = 0; mi < 2; ++mi)
        #pragma unroll
        for (int kk = 0; kk < 4; ++kk)
          wfa[mi][kk] = *reinterpret_cast<const bf16x8*>(wo_ + (w * 32 + mi * 16 + li) * CDIM + kk * 32 + g * 8);
      #pragma unroll
      for (int ni = 0; ni < 4; ++ni)
        #pragma unroll
        for (int kk = 0; kk < 4; ++kk) {
          bf16x8 of = *reinterpret_cast<const bf16x8*>(sm + C_OFF + swz(ni * 16 + li, (kk * 32 + g * 8) * 2, 256));
          accY[0][ni] = __builtin_amdgcn_mfma_f32_16x16x32_bf16(wfa[0][kk], of, accY[0][ni], 0, 0, 0);
          accY[1][ni] = __builtin_amdgcn_mfma_f32_16x16x32_bf16(wfa[1][kk], of, accY[1][ni], 0, 0, 0);
        }
      float* yb = out + (size_t)bb * (NTOK * CDIM);
      #pragma unroll
      for (int mi = 0; mi < 2; ++mi) {
        int dout0 = w * 32 + mi * 16 + g * 4;
        float4 bo4 = *reinterpret_cast<const float4*>(bo + dout0);
        #pragma unroll
        for (int ni = 0; ni < 4; ++ni) {
          int i = ni * 16 + li;
          f32x4 y = accY[mi][ni];
          y.x += bo4.x; y.y += bo4.y; y.z += bo4.z; y.w += bo4.w;
          *reinterpret_cast<f32x4*>(yb + i * CDIM + dout0) = y;
        }
      }
    }
    __syncthreads();   // Bu: Y's C-reads done; next iteration may reuse C
  };

  run(b0, true, b1);
  run(b1, false, 0);
  #undef LDA
}

extern "C" void kernel_launch(void* const* d_in, const int* in_sizes, int n_in,
                              void* d_out, int out_size, void* d_ws, size_t ws_size,
                              hipStream_t stream) {
  const float* x    = (const float*)d_in[0];
  const float* ent  = (const float*)d_in[1];
  const float* wq   = (const float*)d_in[2];
  const float* bq   = (const float*)d_in[3];
  const float* wk   = (const float*)d_in[4];
  const float* bk   = (const float*)d_in[5];
  const float* wv   = (const float*)d_in[6];
  const float* bv   = (const float*)d_in[7];
  const float* wo   = (const float*)d_in[8];
  const float* bo   = (const float*)d_in[9];
  const int*   beta = (const int*)d_in[10];

  short* wbf = (short*)d_ws;             // 4 x 128x128 bf16 = 128 KB
  const int B = in_sizes[0] / (NTOK * CDIM);

  wconv_kernel<<<16, 256, 0, stream>>>(wq, wk, wv, wo, wbf);
  fused_attn<<<B / 2, 256, 0, stream>>>(x, ent, wbf, bq, bk, bv, bo, beta, (float*)d_out);
}

// Round 8
// 107.655 us; speedup vs baseline: 1.5932x; 1.5932x over previous
//
#include <hip/hip_runtime.h>
#include <hip/hip_bf16.h>

#define NTOK 64
#define CDIM 128
#define SCALE 0.17677669529663688f   // 1/sqrt(32), folded into Wq/bq

typedef __attribute__((ext_vector_type(4))) float  f32x4;
typedef __attribute__((ext_vector_type(8))) short  bf16x8;
typedef __attribute__((ext_vector_type(4))) short  s16x4;

__device__ __forceinline__ s16x4 pk4(f32x4 v) {
  union { __hip_bfloat162 h[2]; s16x4 s; } u;
  u.h[0] = __float22bfloat162_rn(float2{v.x, v.y});
  u.h[1] = __float22bfloat162_rn(float2{v.z, v.w});
  return u.s;
}

// XOR-swizzle within a row: 16B granule, 3 row bits
__device__ __forceinline__ int swz(int row, int cb, int stride) {
  return row * stride + (cb ^ ((row & 7) << 4));
}
// for 64B rows (P half-tiles not used here; 128B rows use swz with stride 128)

__global__ void wconv_kernel(const float* __restrict__ wq, const float* __restrict__ wk,
                             const float* __restrict__ wv, const float* __restrict__ wo,
                             short* __restrict__ wbf) {
  int t = (blockIdx.x * 256 + threadIdx.x) * 4;   // 16 blocks
  f32x4 a = *reinterpret_cast<const f32x4*>(wq + t);
  a.x *= SCALE; a.y *= SCALE; a.z *= SCALE; a.w *= SCALE;   // fold softmax scale into Wq
  f32x4 b = *reinterpret_cast<const f32x4*>(wk + t);
  f32x4 c = *reinterpret_cast<const f32x4*>(wv + t);
  f32x4 d = *reinterpret_cast<const f32x4*>(wo + t);
  *reinterpret_cast<s16x4*>(wbf + t)         = pk4(a);
  *reinterpret_cast<s16x4*>(wbf + 16384 + t) = pk4(b);
  *reinterpret_cast<s16x4*>(wbf + 32768 + t) = pk4(c);
  *reinterpret_cast<s16x4*>(wbf + 49152 + t) = pk4(d);
}

// LDS regions (byte offsets), time-multiplexed (R2-validated plan):
//   A [0,16K):   X -> Q -> P(heads 0,1)
//   B [16K,32K): K -> P(heads 2,3)
//   C [32K,48K): Vt -> O
#define A_OFF    0
#define B_OFF    16384
#define C_OFF    32768
#define SMEM_BYTES 49152

__global__ __launch_bounds__(256, 3) void fused_attn(
    const float* __restrict__ x, const float* __restrict__ ent,
    const short* __restrict__ wbf,
    const float* __restrict__ bq, const float* __restrict__ bk,
    const float* __restrict__ bv, const float* __restrict__ bo,
    const int* __restrict__ beta, float* __restrict__ out)
{
  __shared__ unsigned char sm[SMEM_BYTES];
  const int tid  = threadIdx.x;
  const int lane = tid & 63;
  const int w    = tid >> 6;        // wave id 0..3 (= head id in attn phases)
  const int g    = lane >> 4;       // 16-lane group 0..3
  const int li   = lane & 15;
  const int b    = blockIdx.x;

  // ---------- phase 0: stage X (fp32 -> bf16, swizzled) into A ----------
  {
    const float* xb = x + (size_t)b * (NTOK * CDIM);
    #pragma unroll
    for (int it = 0; it < 8; ++it) {
      int f = (tid + 256 * it) * 4;
      int row = f >> 7, col = f & 127;
      f32x4 v = *reinterpret_cast<const f32x4*>(xb + f);
      *reinterpret_cast<s16x4*>(sm + A_OFF + swz(row, col * 2, 256)) = pk4(v);
    }
  }
  __syncthreads();   // B0: X staged

  // Preload all X fragments
  bf16x8 xf[4][4];
  #pragma unroll
  for (int ti = 0; ti < 4; ++ti)
    #pragma unroll
    for (int kk = 0; kk < 4; ++kk)
      xf[ti][kk] = *reinterpret_cast<const bf16x8*>(sm + A_OFF + swz(ti * 16 + li, (kk * 32 + g * 8) * 2, 256));

  __syncthreads();   // B1: X in regs; region A may be overwritten

  const f32x4 zero4 = {0.f, 0.f, 0.f, 0.f};

  // ---------- phase 1a: V (wave w -> d in [32w,32w+32)) -> Vt in C ----------
  {
    const short* wv_ = wbf + 32768;
    f32x4 accv[4][2];
    #pragma unroll
    for (int mi = 0; mi < 4; ++mi) { accv[mi][0] = zero4; accv[mi][1] = zero4; }
    bf16x8 bfv[2][4];
    #pragma unroll
    for (int n2 = 0; n2 < 2; ++n2)
      #pragma unroll
      for (int kk = 0; kk < 4; ++kk)
        bfv[n2][kk] = *reinterpret_cast<const bf16x8*>(wv_ + (w * 32 + n2 * 16 + li) * CDIM + kk * 32 + g * 8);
    __builtin_amdgcn_s_setprio(1);
    #pragma unroll
    for (int mi = 0; mi < 4; ++mi)
      #pragma unroll
      for (int n2 = 0; n2 < 2; ++n2)
        #pragma unroll
        for (int kk = 0; kk < 4; ++kk)
          accv[mi][n2] = __builtin_amdgcn_mfma_f32_16x16x32_bf16(xf[mi][kk], bfv[n2][kk], accv[mi][n2], 0, 0, 0);
    __builtin_amdgcn_s_setprio(0);
    #pragma unroll
    for (int mi = 0; mi < 4; ++mi)
      #pragma unroll
      for (int n2 = 0; n2 < 2; ++n2) {
        int d = w * 32 + n2 * 16 + li;
        float bb = bv[d];
        f32x4 v = accv[mi][n2];
        v.x += bb; v.y += bb; v.z += bb; v.w += bb;
        *reinterpret_cast<s16x4*>(sm + C_OFF + swz(d, (mi * 16 + g * 4) * 2, 128)) = pk4(v);
      }
  }

  // ---------- phase 1b: Q,K (swapped: Dt = W * X^T), streamed per 16-dout tile ----------
  // waves 0,1 -> Q into A ; waves 2,3 -> K into B
  {
    const short* wmat = wbf + ((w < 2) ? 0 : 16384);
    const float* bias = (w < 2) ? bq : bk;
    const float bsc   = (w < 2) ? SCALE : 1.0f;
    const int dbase   = (w & 1) * 64;
    const int qkoff   = (w < 2) ? A_OFF : B_OFF;

    #pragma unroll
    for (int mi = 0; mi < 4; ++mi) {
      bf16x8 af[4];
      #pragma unroll
      for (int kk = 0; kk < 4; ++kk)
        af[kk] = *reinterpret_cast<const bf16x8*>(wmat + (dbase + mi * 16 + li) * CDIM + kk * 32 + g * 8);
      f32x4 acc[4];
      #pragma unroll
      for (int ni = 0; ni < 4; ++ni) acc[ni] = zero4;
      __builtin_amdgcn_s_setprio(1);
      #pragma unroll
      for (int ni = 0; ni < 4; ++ni)
        #pragma unroll
        for (int kk = 0; kk < 4; ++kk)
          acc[ni] = __builtin_amdgcn_mfma_f32_16x16x32_bf16(af[kk], xf[ni][kk], acc[ni], 0, 0, 0);
      __builtin_amdgcn_s_setprio(0);
      int d0 = dbase + mi * 16 + g * 4;
      float4 b4 = *reinterpret_cast<const float4*>(bias + d0);
      b4.x *= bsc; b4.y *= bsc; b4.z *= bsc; b4.w *= bsc;
      #pragma unroll
      for (int ni = 0; ni < 4; ++ni) {
        f32x4 v = acc[ni];
        v.x += b4.x; v.y += b4.y; v.z += b4.z; v.w += b4.w;
        *reinterpret_cast<s16x4*>(sm + qkoff + swz(ni * 16 + li, d0 * 2, 256)) = pk4(v);
      }
    }
  }
  __syncthreads();   // B2: Q,K,Vt ready

  // ---------- phase 2: scores (swapped: St = K * Q^T, scale pre-folded) + softmax ----------
  f32x4 st[4][4];  // [mj (j-tile)][ni (i-tile)]
  {
    bf16x8 kf[4], qf[4];
    int cb = (w * 32 + g * 8) * 2;   // d-range of head w
    #pragma unroll
    for (int t = 0; t < 4; ++t) {
      kf[t] = *reinterpret_cast<const bf16x8*>(sm + B_OFF + swz(t * 16 + li, cb, 256));
      qf[t] = *reinterpret_cast<const bf16x8*>(sm + A_OFF + swz(t * 16 + li, cb, 256));
    }
    __builtin_amdgcn_s_setprio(1);
    #pragma unroll
    for (int mj = 0; mj < 4; ++mj)
      #pragma unroll
      for (int ni = 0; ni < 4; ++ni)
        st[mj][ni] = __builtin_amdgcn_mfma_f32_16x16x32_bf16(kf[mj], qf[ni], zero4, 0, 0, 0);
    __builtin_amdgcn_s_setprio(0);
  }
  // gate direct from global: j = mj*16 + g*4 + r (L1-broadcast reads)
  float4 gv[4];
  {
    const float nb = -(float)beta[0];
    const float* eb = ent + (size_t)b * NTOK;
    #pragma unroll
    for (int mj = 0; mj < 4; ++mj) {
      float4 e = *reinterpret_cast<const float4*>(eb + mj * 16 + g * 4);
      gv[mj].x = nb * e.x; gv[mj].y = nb * e.y; gv[mj].z = nb * e.z; gv[mj].w = nb * e.w;
    }
  }

  // no-max softmax (logits bounded; validated R4/R6/R7)
  #pragma unroll
  for (int ni = 0; ni < 4; ++ni) {
    float sum = 0.f;
    #pragma unroll
    for (int mj = 0; mj < 4; ++mj) {
      f32x4 v = st[mj][ni];
      v.x = __expf(v.x + gv[mj].x); v.y = __expf(v.y + gv[mj].y);
      v.z = __expf(v.z + gv[mj].z); v.w = __expf(v.w + gv[mj].w);
      st[mj][ni] = v;
      sum += v.x + v.y + v.z + v.w;
    }
    sum += __shfl_xor(sum, 16);
    sum += __shfl_xor(sum, 32);
    float inv = 1.f / (sum + 1e-9f);
    #pragma unroll
    for (int mj = 0; mj < 4; ++mj) {
      st[mj][ni].x *= inv; st[mj][ni].y *= inv;
      st[mj][ni].z *= inv; st[mj][ni].w *= inv;
    }
  }
  __syncthreads();   // B3: all waves done reading Q/K; P may overwrite A/B

  // store P^T regs -> P[i][j] packed b64 (head w at sm + w*8192, spans A then B)
  unsigned char* pb = sm + w * 8192;
  #pragma unroll
  for (int mj = 0; mj < 4; ++mj) {
    int cb = (mj * 16 + g * 4) * 2;  // j0
    #pragma unroll
    for (int ni = 0; ni < 4; ++ni)
      *reinterpret_cast<s16x4*>(pb + swz(ni * 16 + li, cb, 128)) = pk4(st[mj][ni]);
  }

  // ---------- phase 3: PV (swapped: Ot = Vt * P^T) ----------
  {
    f32x4 accO[2][4];
    #pragma unroll
    for (int md = 0; md < 2; ++md)
      #pragma unroll
      for (int ni = 0; ni < 4; ++ni) accO[md][ni] = zero4;
    bf16x8 vf[2][2];
    #pragma unroll
    for (int md = 0; md < 2; ++md)
      #pragma unroll
      for (int ks = 0; ks < 2; ++ks)
        vf[md][ks] = *reinterpret_cast<const bf16x8*>(sm + C_OFF + swz(w * 32 + md * 16 + li, (ks * 32 + g * 8) * 2, 128));
    bf16x8 pf[4][2];
    #pragma unroll
    for (int ni = 0; ni < 4; ++ni)
      #pragma unroll
      for (int ks = 0; ks < 2; ++ks)
        pf[ni][ks] = *reinterpret_cast<const bf16x8*>(pb + swz(ni * 16 + li, (ks * 32 + g * 8) * 2, 128));
    __builtin_amdgcn_s_setprio(1);
    #pragma unroll
    for (int md = 0; md < 2; ++md)
      #pragma unroll
      for (int ni = 0; ni < 4; ++ni)
        #pragma unroll
        for (int ks = 0; ks < 2; ++ks)
          accO[md][ni] = __builtin_amdgcn_mfma_f32_16x16x32_bf16(vf[md][ks], pf[ni][ks], accO[md][ni], 0, 0, 0);
    __builtin_amdgcn_s_setprio(0);
    __syncthreads();   // B4: all waves done reading Vt; O may overwrite C
    // store Ot[dd][i] -> O[i][c] in C (values r are consecutive c)
    #pragma unroll
    for (int md = 0; md < 2; ++md) {
      int cb = (w * 32 + md * 16 + g * 4) * 2;  // d0
      #pragma unroll
      for (int ni = 0; ni < 4; ++ni)
        *reinterpret_cast<s16x4*>(sm + C_OFF + swz(ni * 16 + li, cb, 256)) = pk4(accO[md][ni]);
    }
  }
  __syncthreads();   // B5: O ready

  // ---------- phase 4: out-proj swapped (Yt = Wo * O^T) -> float4 stores ----------
  {
    const short* wo_ = wbf + 49152;
    f32x4 accY[2][4];   // [mi (dout tile)][ni (i tile)]
    #pragma unroll
    for (int mi = 0; mi < 2; ++mi)
      #pragma unroll
      for (int ni = 0; ni < 4; ++ni) accY[mi][ni] = zero4;
    bf16x8 wfa[2][4];
    #pragma unroll
    for (int mi = 0; mi < 2; ++mi)
      #pragma unroll
      for (int kk = 0; kk < 4; ++kk)
        wfa[mi][kk] = *reinterpret_cast<const bf16x8*>(wo_ + (w * 32 + mi * 16 + li) * CDIM + kk * 32 + g * 8);
    bf16x8 of[4][4];
    #pragma unroll
    for (int ni = 0; ni < 4; ++ni)
      #pragma unroll
      for (int kk = 0; kk < 4; ++kk)
        of[ni][kk] = *reinterpret_cast<const bf16x8*>(sm + C_OFF + swz(ni * 16 + li, (kk * 32 + g * 8) * 2, 256));
    __builtin_amdgcn_s_setprio(1);
    #pragma unroll
    for (int mi = 0; mi < 2; ++mi)
      #pragma unroll
      for (int ni = 0; ni < 4; ++ni)
        #pragma unroll
        for (int kk = 0; kk < 4; ++kk)
          accY[mi][ni] = __builtin_amdgcn_mfma_f32_16x16x32_bf16(wfa[mi][kk], of[ni][kk], accY[mi][ni], 0, 0, 0);
    __builtin_amdgcn_s_setprio(0);
    float* yb = out + (size_t)b * (NTOK * CDIM);
    #pragma unroll
    for (int mi = 0; mi < 2; ++mi) {
      int dout0 = w * 32 + mi * 16 + g * 4;
      float4 bo4 = *reinterpret_cast<const float4*>(bo + dout0);
      #pragma unroll
      for (int ni = 0; ni < 4; ++ni) {
        int i = ni * 16 + li;
        f32x4 y = accY[mi][ni];
        y.x += bo4.x; y.y += bo4.y; y.z += bo4.z; y.w += bo4.w;
        *reinterpret_cast<f32x4*>(yb + i * CDIM + dout0) = y;
      }
    }
  }
}

extern "C" void kernel_launch(void* const* d_in, const int* in_sizes, int n_in,
                              void* d_out, int out_size, void* d_ws, size_t ws_size,
                              hipStream_t stream) {
  const float* x    = (const float*)d_in[0];
  const float* ent  = (const float*)d_in[1];
  const float* wq   = (const float*)d_in[2];
  const float* bq   = (const float*)d_in[3];
  const float* wk   = (const float*)d_in[4];
  const float* bk   = (const float*)d_in[5];
  const float* wv   = (const float*)d_in[6];
  const float* bv   = (const float*)d_in[7];
  const float* wo   = (const float*)d_in[8];
  const float* bo   = (const float*)d_in[9];
  const int*   beta = (const int*)d_in[10];

  short* wbf = (short*)d_ws;             // 4 x 128x128 bf16 = 128 KB
  const int B = in_sizes[0] / (NTOK * CDIM);

  wconv_kernel<<<16, 256, 0, stream>>>(wq, wk, wv, wo, wbf);
  fused_attn<<<B, 256, 0, stream>>>(x, ent, wbf, bq, bk, bv, bo, beta, (float*)d_out);
}